// Round 9
// baseline (605.172 us; speedup 1.0000x reference)
//
#include <hip/hip_runtime.h>

// GlobalAttentionPooling: tensor_square_0e -> selu -> @W -> segment softmax -> weighted segment sum
// N nodes, 80 f32 ft (32 scalar + 16 x 3-vec), NG=1024 graphs (sorted batch_index), F=664.
//
// Math identities (validated rounds 1-4, absmax 3.9e-3):
//   selu const term cancels in softmax; pre-scale s by sqrt(log2e), v by sqrt(log2e/sqrt3)
//   so pair products are f*log2e -> exp2 directly. out_g = (sum nf*ex)/z_g.
//
// Round-14: ABLATION SPLIT, take 2. r13's p1 (TPB=256) flipped the allocator into spill mode
//   (WRITE 749MB, 460us) -- instrument failed before measuring. Codegen is tri-stable
//   (sink/hold/spill); only (TPB=128, launch_bounds(128,4)) is measured-clean (r12: VGPR=40,
//   WRITE 19MB, 84us fused). This round: identical split but p1 compiled with r12's exact
//   recipe. p2 = r5-shape (320/320, bounds(320,2)), known-clean.
//   Readout drives round 15: p1-dominant -> 2-nodes/thread in p1 (ds_read amortize + ILP);
//   p2-dominant -> segment-path rework. Falsifier on instrument: p1 WRITE > 30MB = spilled.

typedef float f2 __attribute__((ext_vector_type(2)));

#define C0 32
#define C1 16
#define NODE_F 80
#define NG_CONST 1024
#define TPB1 128                // p1: threads per block (1 thread/node) -- r12 recipe
#define NPB2 320                // p2: nodes per block
#define TPB2 320

#define SELU_SCALE 1.0507009873554804934193349852946
#define SELU_ALPHA 1.6732632423543772848170429916717
#define LOG2E      1.4426950408889634073599246810019

#define CS_SCALE 1.2011224087864498f    // sqrt(log2e)
#define CV_SCALE 0.91271231102878545f   // sqrt(log2e/sqrt(3))

// ws float layout:
//   [0, 81920)        S accum: [1024 graphs][80 ch]
//   [81920, 82944)    z accum: [1024]
//   [82944, 84224)    Wpad: 512 f2 scalar rows (32x16) then 128 f2 vec rows (16x8)
//   [84224, 84224+N)  exbuf
#define WS_S 0
#define WS_Z 81920
#define WS_W 82944
#define WS_EX 84224

__device__ __forceinline__ int ks_idx(int i, int j) { return i * C0 - (i * (i - 1)) / 2 + (j - i); }
__device__ __forceinline__ int kv_idx(int i, int j) { return 528 + i * C1 - (i * (i - 1)) / 2 + (j - i); }

// zero the accumulators + build padded W tables
__global__ __launch_bounds__(256) void prep_kernel(
    const float* __restrict__ W, float* __restrict__ ws)
{
    const int t = blockIdx.x * blockDim.x + threadIdx.x;
    if (t < 82944) {
        ws[t] = 0.0f;                       // S and z
    } else {
        int u = t - 82944;
        if (u < 512) {                      // Ws: i in [0,32), q in [0,16)
            int i = u >> 4, q = u & 15;
            int j0 = 2 * q, j1 = 2 * q + 1;
            ws[WS_W + 2 * u]     = (j0 >= i) ? W[ks_idx(i, j0)] : 0.0f;
            ws[WS_W + 2 * u + 1] = (j1 >= i) ? W[ks_idx(i, j1)] : 0.0f;
        } else if (u < 640) {               // Wv: i in [0,16), q in [0,8)
            int v = u - 512;
            int i = v >> 3, q = v & 7;
            int j0 = 2 * q, j1 = 2 * q + 1;
            ws[WS_W + 1024 + 2 * v]     = (j0 >= i) ? W[kv_idx(i, j0)] : 0.0f;
            ws[WS_W + 1024 + 2 * v + 1] = (j1 >= i) ? W[kv_idx(i, j1)] : 0.0f;
        }
    }
}

// ---- phase 1 standalone: attention logit -> ex, one thread per node (r12 codegen recipe) ----
__global__ __launch_bounds__(TPB1, 4) void p1_kernel(
    const float* __restrict__ nf, const float* __restrict__ ws,
    float* __restrict__ exbuf, int N)
{
    __shared__ __align__(16) float Wlds[1280];

    const int tid  = threadIdx.x;
    const int n    = blockIdx.x * TPB1 + tid;
    const float4* g4 = (const float4*)nf;

    #pragma unroll
    for (int u = tid; u < 1280; u += TPB1) Wlds[u] = ws[WS_W + u];

    const bool valid = (n < N);
    const int  nn    = valid ? n : (N - 1);
    __syncthreads();                        // Wlds ready

    const float4* gp = g4 + (size_t)nn * 20;
    const f2* WsL = (const f2*)Wlds;          // 512 f2
    const f2* WvL = (const f2*)(Wlds + 1024); // 128 f2

    // scalar half -> s2 in registers, PINNED against load-sinking (r12 codegen)
    f2 s2[C0 / 2];
    {
        float4 rs[8];
        #pragma unroll
        for (int q = 0; q < 8; ++q) rs[q] = gp[q];
        #pragma unroll
        for (int q = 0; q < 8; ++q) {
            s2[2 * q]     = f2{rs[q].x, rs[q].y} * CS_SCALE;
            s2[2 * q + 1] = f2{rs[q].z, rs[q].w} * CS_SCALE;
        }
    }
    #pragma unroll
    for (int q = 0; q < C0 / 2; ++q) asm volatile("" : "+v"(s2[q]));

    f2 accA[2], accB[2];
    accA[0] = (f2)0.f; accA[1] = (f2)0.f; accB[0] = (f2)0.f; accB[1] = (f2)0.f;

    // scalar triangle rows 0..15
    #pragma unroll
    for (int i = 0; i < 16; ++i) {
        const float si = (i & 1) ? s2[i >> 1].y : s2[i >> 1].x;
        const f2 si2 = f2{si, si};
        #pragma unroll
        for (int q = i >> 1; q < C0 / 2; ++q) {
            f2 f = si2 * s2[q];
            f2 p = __builtin_elementwise_max(f, (f2)0.f);
            f2 m = __builtin_elementwise_min(f, (f2)0.f);
            f2 e; e.x = __builtin_amdgcn_exp2f(m.x);
                  e.y = __builtin_amdgcn_exp2f(m.y);
            f2 w = WsL[i * 16 + q];             // broadcast ds_read_b64, pad slots = 0
            accA[q & 1] = __builtin_elementwise_fma(w, p, accA[q & 1]);
            accB[q & 1] = __builtin_elementwise_fma(w, e, accB[q & 1]);
        }
    }

    // issue vector-half global loads; rows 16..31 cover their HBM latency
    float4 rv[12];
    #pragma unroll
    for (int q = 0; q < 12; ++q) rv[q] = gp[8 + q];

    // scalar triangle rows 16..31
    #pragma unroll
    for (int i = 16; i < 32; ++i) {
        const float si = (i & 1) ? s2[i >> 1].y : s2[i >> 1].x;
        const f2 si2 = f2{si, si};
        #pragma unroll
        for (int q = i >> 1; q < C0 / 2; ++q) {
            f2 f = si2 * s2[q];
            f2 p = __builtin_elementwise_max(f, (f2)0.f);
            f2 m = __builtin_elementwise_min(f, (f2)0.f);
            f2 e; e.x = __builtin_amdgcn_exp2f(m.x);
                  e.y = __builtin_amdgcn_exp2f(m.y);
            f2 w = WsL[i * 16 + q];
            accA[q & 1] = __builtin_elementwise_fma(w, p, accA[q & 1]);
            accB[q & 1] = __builtin_elementwise_fma(w, e, accB[q & 1]);
        }
    }

    // vector part: build vp (unpinned -- s2 dead here), triangle
    f2 vp[C1 / 2][3];
    {
        const float* rvf = (const float*)rv;
        #pragma unroll
        for (int q = 0; q < C1 / 2; ++q) {
            #pragma unroll
            for (int c = 0; c < 3; ++c)
                vp[q][c] = f2{rvf[6 * q + c], rvf[6 * q + 3 + c]} * CV_SCALE;
        }
    }

    #pragma unroll
    for (int i = 0; i < C1; ++i) {
        const int iq = i >> 1;
        const float vi0 = (i & 1) ? vp[iq][0].y : vp[iq][0].x;
        const float vi1 = (i & 1) ? vp[iq][1].y : vp[iq][1].x;
        const float vi2 = (i & 1) ? vp[iq][2].y : vp[iq][2].x;
        #pragma unroll
        for (int q = i >> 1; q < C1 / 2; ++q) {
            f2 f = vp[q][0] * f2{vi0, vi0};
            f = __builtin_elementwise_fma(vp[q][1], f2{vi1, vi1}, f);
            f = __builtin_elementwise_fma(vp[q][2], f2{vi2, vi2}, f);
            f2 p = __builtin_elementwise_max(f, (f2)0.f);
            f2 m = __builtin_elementwise_min(f, (f2)0.f);
            f2 e; e.x = __builtin_amdgcn_exp2f(m.x);
                  e.y = __builtin_amdgcn_exp2f(m.y);
            f2 w = WvL[i * 8 + q];
            accA[q & 1] = __builtin_elementwise_fma(w, p, accA[q & 1]);
            accB[q & 1] = __builtin_elementwise_fma(w, e, accB[q & 1]);
        }
    }

    const float A1 = accA[0].x + accA[0].y + accA[1].x + accA[1].y;
    const float A2 = accB[0].x + accB[0].y + accB[1].x + accB[1].y;
    const float l2 = fmaf((float)SELU_SCALE, A1,
                          (float)(SELU_SCALE * SELU_ALPHA * LOG2E) * A2);
    if (valid) exbuf[n] = __builtin_amdgcn_exp2f(l2);
}

// ---- phase 2 standalone: weighted segment sum, r5 shape (16 chunks x 20 cols x 20 nodes) ----
__global__ __launch_bounds__(TPB2, 2) void p2_kernel(
    const float* __restrict__ nf, const int* __restrict__ bi,
    const float* __restrict__ exbuf, float* __restrict__ S,
    float* __restrict__ z, int N)
{
    __shared__ float exl[NPB2];
    __shared__ int   bil[NPB2];

    const int tid  = threadIdx.x;
    const int base = blockIdx.x * NPB2;
    const float4* g4 = (const float4*)nf;

    const int idx0 = base + tid;
    bil[tid] = bi[idx0 > N - 1 ? N - 1 : idx0];
    exl[tid] = (idx0 < N) ? exbuf[idx0] : 0.0f;
    __syncthreads();

    const int no = tid / 20;       // 0..15
    const int c4 = tid % 20;
    int cg = bil[no * 20];
    float4 acc = make_float4(0.f, 0.f, 0.f, 0.f);
    float  zacc = 0.0f;

    #pragma unroll
    for (int k = 0; k < 20; ++k) {
        const int nl = no * 20 + k;
        const int g2 = bil[nl];
        if (g2 != cg) {
            unsafeAtomicAdd(&S[cg * NODE_F + c4 * 4 + 0], acc.x);
            unsafeAtomicAdd(&S[cg * NODE_F + c4 * 4 + 1], acc.y);
            unsafeAtomicAdd(&S[cg * NODE_F + c4 * 4 + 2], acc.z);
            unsafeAtomicAdd(&S[cg * NODE_F + c4 * 4 + 3], acc.w);
            if (c4 == 0) unsafeAtomicAdd(&z[cg], zacc);
            acc = make_float4(0.f, 0.f, 0.f, 0.f); zacc = 0.0f; cg = g2;
        }
        int idx = base + nl; if (idx > N - 1) idx = N - 1;   // pad nodes have w=0
        const float  w = exl[nl];
        const float4 v = g4[(size_t)idx * 20 + c4];
        acc.x = fmaf(v.x, w, acc.x); acc.y = fmaf(v.y, w, acc.y);
        acc.z = fmaf(v.z, w, acc.z); acc.w = fmaf(v.w, w, acc.w);
        zacc += w;
    }
    unsafeAtomicAdd(&S[cg * NODE_F + c4 * 4 + 0], acc.x);
    unsafeAtomicAdd(&S[cg * NODE_F + c4 * 4 + 1], acc.y);
    unsafeAtomicAdd(&S[cg * NODE_F + c4 * 4 + 2], acc.z);
    unsafeAtomicAdd(&S[cg * NODE_F + c4 * 4 + 3], acc.w);
    if (c4 == 0) unsafeAtomicAdd(&z[cg], zacc);
}

__global__ __launch_bounds__(256) void divide_kernel(
    const float* __restrict__ S, const float* __restrict__ z,
    float* __restrict__ out)
{
    const int t = blockIdx.x * blockDim.x + threadIdx.x;
    if (t >= NG_CONST * NODE_F) return;
    const float zz = z[t / NODE_F];
    out[t] = (zz > 0.0f) ? (S[t] / zz) : 0.0f;
}

extern "C" void kernel_launch(void* const* d_in, const int* in_sizes, int n_in,
                              void* d_out, int out_size, void* d_ws, size_t ws_size,
                              hipStream_t stream) {
    const float* nf = (const float*)d_in[0];   // (N, 80) f32
    const int*   bi = (const int*)d_in[1];     // (N,) i32 sorted
    // d_in[2] = num_graphs (static 1024)
    const float* W  = (const float*)d_in[3];   // (664,) f32
    float* out = (float*)d_out;

    const int N = in_sizes[0] / NODE_F;
    float* ws = (float*)d_ws;
    float* S  = ws + WS_S;
    float* z  = ws + WS_Z;
    float* ex = ws + WS_EX;

    hipLaunchKernelGGL(prep_kernel, dim3(332), dim3(256), 0, stream, W, ws);
    hipLaunchKernelGGL(p1_kernel, dim3((N + TPB1 - 1) / TPB1), dim3(TPB1), 0, stream,
                       nf, ws, ex, N);
    hipLaunchKernelGGL(p2_kernel, dim3((N + NPB2 - 1) / NPB2), dim3(TPB2), 0, stream,
                       nf, bi, ex, S, z, N);
    hipLaunchKernelGGL(divide_kernel, dim3((NG_CONST * NODE_F + 255) / 256), dim3(256),
                       0, stream, S, z, out);
}

// Round 10
// 217.255 us; speedup vs baseline: 2.7855x; 2.7855x over previous
//
#include <hip/hip_runtime.h>

// GlobalAttentionPooling: tensor_square_0e -> selu -> @W -> segment softmax -> weighted segment sum
// N nodes, 80 f32 ft (32 scalar + 16 x 3-vec), NG=1024 graphs (sorted batch_index), F=664.
//
// Math identities (validated rounds 1-4, absmax 3.9e-3):
//   selu const term cancels in softmax; pre-scale s by sqrt(log2e), v by sqrt(log2e/sqrt3)
//   so pair products are f*log2e -> exp2 directly. out_g = (sum nf*ex)/z_g.
//
// Round-15: r6's lane-pair split, confound removed. Ledger: per-wave phase-1 latency ~55us
//   at ~8us issue, NO pipe saturated (VALU 38 / trans ~12 / LDS ~19 / HBM 20%), ~3 waves/SIMD
//   resident (grid-limited, 4688 waves fixed by 1-thread-per-node). r6 proved the split
//   doubles occupancy; it lost to a self-inflicted phase-2 flush doubling (WRITE 136MB).
//   r13/r14: standalone-p1 spills regardless of recipe -> allocator outcome not portable
//   across kernel contexts (rule #19); split instrument abandoned.
//   This round: NPB=320 (phase 2 VERBATIM r5/r12, tid<320 -> flush count/concurrency
//   unchanged, WRITE stays ~20MB) + TPB=640 (2 lanes/node, r6's validated triangle code:
//   9375 waves, 10-wave blocks, 3 blocks/CU = 30 waves/CU resident vs r12's ~12).
//   bounds(640,8) mirrors r6's clean cap-64 outcome (VGPR=32).
//   Falsifiers: WRITE>35MB (phase-2 poisoned) / VGPR spill / main>=80 with clean counters
//   (TLP lever dead -> per-wave latency intrinsic).

typedef float f2 __attribute__((ext_vector_type(2)));

#define C0 32
#define C1 16
#define NODE_F 80
#define NG_CONST 1024
#define NPB 320                 // nodes per block
#define TPB 640                 // 2 lanes per node

#define SELU_SCALE 1.0507009873554804934193349852946
#define SELU_ALPHA 1.6732632423543772848170429916717
#define LOG2E      1.4426950408889634073599246810019

#define CS_SCALE 1.2011224087864498f    // sqrt(log2e)
#define CV_SCALE 0.91271231102878545f   // sqrt(log2e/sqrt(3))

// ws float layout:
//   [0, 81920)        S accum: [1024 graphs][80 ch]
//   [81920, 82944)    z accum: [1024]
//   [82944, 84224)    Wpad: 512 f2 scalar rows (32x16) then 128 f2 vec rows (16x8)
#define WS_S 0
#define WS_Z 81920
#define WS_W 82944

__device__ __forceinline__ int ks_idx(int i, int j) { return i * C0 - (i * (i - 1)) / 2 + (j - i); }
__device__ __forceinline__ int kv_idx(int i, int j) { return 528 + i * C1 - (i * (i - 1)) / 2 + (j - i); }

// zero the accumulators + build padded W tables
__global__ __launch_bounds__(256) void prep_kernel(
    const float* __restrict__ W, float* __restrict__ ws)
{
    const int t = blockIdx.x * blockDim.x + threadIdx.x;
    if (t < 82944) {
        ws[t] = 0.0f;                       // S and z
    } else {
        int u = t - 82944;
        if (u < 512) {                      // Ws: i in [0,32), q in [0,16)
            int i = u >> 4, q = u & 15;
            int j0 = 2 * q, j1 = 2 * q + 1;
            ws[WS_W + 2 * u]     = (j0 >= i) ? W[ks_idx(i, j0)] : 0.0f;
            ws[WS_W + 2 * u + 1] = (j1 >= i) ? W[ks_idx(i, j1)] : 0.0f;
        } else if (u < 640) {               // Wv: i in [0,16), q in [0,8)
            int v = u - 512;
            int i = v >> 3, q = v & 7;
            int j0 = 2 * q, j1 = 2 * q + 1;
            ws[WS_W + 1024 + 2 * v]     = (j0 >= i) ? W[kv_idx(i, j0)] : 0.0f;
            ws[WS_W + 1024 + 2 * v + 1] = (j1 >= i) ? W[kv_idx(i, j1)] : 0.0f;
        }
    }
}

__global__ __launch_bounds__(TPB, 8) void main_kernel(
    const float* __restrict__ nf, const int* __restrict__ bi,
    const float* __restrict__ ws, float* __restrict__ S,
    float* __restrict__ z, int N)
{
    __shared__ __align__(16) float Wlds[1280];
    __shared__ float exl[NPB];
    __shared__ int   bil[NPB];

    const int tid  = threadIdx.x;
    const int base = blockIdx.x * NPB;
    const float4* g4 = (const float4*)nf;

    #pragma unroll
    for (int u = tid; u < 1280; u += TPB) Wlds[u] = ws[WS_W + u];

    if (tid < NPB) {
        int idx = base + tid;
        bil[tid] = bi[idx > N - 1 ? N - 1 : idx];
    }

    const int  ln    = tid >> 1;            // local node 0..319
    const int  p     = tid & 1;             // parity: which half of the triangle rows
    const int  n     = base + ln;
    const bool valid = (n < N);
    const int  nn    = valid ? n : (N - 1);
    __syncthreads();                        // Wlds + bil ready

    // ---- phase 1: lane pair shares one node; lane p does rows i with (i&1)==p ----
    float4 row4[20];
    #pragma unroll
    for (int q = 0; q < 20; ++q) row4[q] = g4[(size_t)nn * 20 + q];
    const float* row = (const float*)row4;

    const f2* WsL = (const f2*)Wlds;          // 512 f2
    const f2* WvL = (const f2*)(Wlds + 1024); // 128 f2

    f2 accA[2], accB[2];
    accA[0] = (f2)0.f; accA[1] = (f2)0.f; accB[0] = (f2)0.f; accB[1] = (f2)0.f;

    {   // scalar part: lane handles i = 2k+p, k=0..15 (136 f2-iters per lane)
        f2 s2[C0 / 2];
        #pragma unroll
        for (int q = 0; q < C0 / 2; ++q)
            s2[q] = f2{row[2 * q], row[2 * q + 1]} * CS_SCALE;
        #pragma unroll
        for (int k = 0; k < C0 / 2; ++k) {
            const int i = 2 * k + p;                    // lane-dependent row
            const float si = p ? s2[k].y : s2[k].x;
            const f2 si2 = f2{si, si};
            #pragma unroll
            for (int q = k; q < C0 / 2; ++q) {
                f2 f = si2 * s2[q];
                f2 pp = __builtin_elementwise_max(f, (f2)0.f);
                f2 m  = __builtin_elementwise_min(f, (f2)0.f);
                f2 e; e.x = __builtin_amdgcn_exp2f(m.x);
                      e.y = __builtin_amdgcn_exp2f(m.y);
                f2 w = WsL[i * 16 + q];             // rows 128B apart across lane pair: 2-way, free
                accA[q & 1] = __builtin_elementwise_fma(w, pp, accA[q & 1]);
                accB[q & 1] = __builtin_elementwise_fma(w, e, accB[q & 1]);
            }
        }
    }
    {   // vector part: lane handles i = 2k+p, k=0..7 (36 f2-iters per lane)
        f2 vp[C1 / 2][3];
        #pragma unroll
        for (int q = 0; q < C1 / 2; ++q) {
            #pragma unroll
            for (int c = 0; c < 3; ++c)
                vp[q][c] = f2{row[C0 + 6 * q + c], row[C0 + 6 * q + 3 + c]} * CV_SCALE;
        }
        #pragma unroll
        for (int k = 0; k < C1 / 2; ++k) {
            const int i = 2 * k + p;
            const float vi0 = p ? vp[k][0].y : vp[k][0].x;
            const float vi1 = p ? vp[k][1].y : vp[k][1].x;
            const float vi2 = p ? vp[k][2].y : vp[k][2].x;
            #pragma unroll
            for (int q = k; q < C1 / 2; ++q) {
                f2 f = vp[q][0] * f2{vi0, vi0};
                f = __builtin_elementwise_fma(vp[q][1], f2{vi1, vi1}, f);
                f = __builtin_elementwise_fma(vp[q][2], f2{vi2, vi2}, f);
                f2 pp = __builtin_elementwise_max(f, (f2)0.f);
                f2 m  = __builtin_elementwise_min(f, (f2)0.f);
                f2 e; e.x = __builtin_amdgcn_exp2f(m.x);
                      e.y = __builtin_amdgcn_exp2f(m.y);
                f2 w = WvL[i * 8 + q];
                accA[q & 1] = __builtin_elementwise_fma(w, pp, accA[q & 1]);
                accB[q & 1] = __builtin_elementwise_fma(w, e, accB[q & 1]);
            }
        }
    }

    float A1 = accA[0].x + accA[0].y + accA[1].x + accA[1].y;
    float A2 = accB[0].x + accB[0].y + accB[1].x + accB[1].y;
    A1 += __shfl_xor(A1, 1);                // combine lane-pair halves
    A2 += __shfl_xor(A2, 1);
    const float l2 = fmaf((float)SELU_SCALE, A1,
                          (float)(SELU_SCALE * SELU_ALPHA * LOG2E) * A2);
    if (p == 0) exl[ln] = valid ? __builtin_amdgcn_exp2f(l2) : 0.0f;
    __syncthreads();

    // ---- phase 2 (tid<320): VERBATIM r5/r12 -- 16 chunks x 20 cols x 20 nodes, flush per run ----
    if (tid < NPB) {
        const int no = tid / 20;       // 0..15
        const int c4 = tid % 20;
        int cg = bil[no * 20];
        float4 acc = make_float4(0.f, 0.f, 0.f, 0.f);
        float  zacc = 0.0f;

        #pragma unroll
        for (int k = 0; k < 20; ++k) {
            const int nl = no * 20 + k;
            const int g2 = bil[nl];
            if (g2 != cg) {
                unsafeAtomicAdd(&S[cg * NODE_F + c4 * 4 + 0], acc.x);
                unsafeAtomicAdd(&S[cg * NODE_F + c4 * 4 + 1], acc.y);
                unsafeAtomicAdd(&S[cg * NODE_F + c4 * 4 + 2], acc.z);
                unsafeAtomicAdd(&S[cg * NODE_F + c4 * 4 + 3], acc.w);
                if (c4 == 0) unsafeAtomicAdd(&z[cg], zacc);
                acc = make_float4(0.f, 0.f, 0.f, 0.f); zacc = 0.0f; cg = g2;
            }
            int idx = base + nl; if (idx > N - 1) idx = N - 1;   // pad nodes have w=0
            const float  w = exl[nl];
            const float4 v = g4[(size_t)idx * 20 + c4];
            acc.x = fmaf(v.x, w, acc.x); acc.y = fmaf(v.y, w, acc.y);
            acc.z = fmaf(v.z, w, acc.z); acc.w = fmaf(v.w, w, acc.w);
            zacc += w;
        }
        unsafeAtomicAdd(&S[cg * NODE_F + c4 * 4 + 0], acc.x);
        unsafeAtomicAdd(&S[cg * NODE_F + c4 * 4 + 1], acc.y);
        unsafeAtomicAdd(&S[cg * NODE_F + c4 * 4 + 2], acc.z);
        unsafeAtomicAdd(&S[cg * NODE_F + c4 * 4 + 3], acc.w);
        if (c4 == 0) unsafeAtomicAdd(&z[cg], zacc);
    }
}

__global__ __launch_bounds__(256) void divide_kernel(
    const float* __restrict__ S, const float* __restrict__ z,
    float* __restrict__ out)
{
    const int t = blockIdx.x * blockDim.x + threadIdx.x;
    if (t >= NG_CONST * NODE_F) return;
    const float zz = z[t / NODE_F];
    out[t] = (zz > 0.0f) ? (S[t] / zz) : 0.0f;
}

extern "C" void kernel_launch(void* const* d_in, const int* in_sizes, int n_in,
                              void* d_out, int out_size, void* d_ws, size_t ws_size,
                              hipStream_t stream) {
    const float* nf = (const float*)d_in[0];   // (N, 80) f32
    const int*   bi = (const int*)d_in[1];     // (N,) i32 sorted
    // d_in[2] = num_graphs (static 1024)
    const float* W  = (const float*)d_in[3];   // (664,) f32
    float* out = (float*)d_out;

    const int N = in_sizes[0] / NODE_F;
    float* ws = (float*)d_ws;
    float* S  = ws + WS_S;
    float* z  = ws + WS_Z;

    hipLaunchKernelGGL(prep_kernel, dim3(332), dim3(256), 0, stream, W, ws);
    hipLaunchKernelGGL(main_kernel, dim3((N + NPB - 1) / NPB), dim3(TPB), 0, stream,
                       nf, bi, ws, S, z, N);
    hipLaunchKernelGGL(divide_kernel, dim3((NG_CONST * NODE_F + 255) / 256), dim3(256),
                       0, stream, S, z, out);
}

// Round 11
// 182.292 us; speedup vs baseline: 3.3198x; 1.1918x over previous
//
#include <hip/hip_runtime.h>

// GlobalAttentionPooling: tensor_square_0e -> selu -> @W -> segment softmax -> weighted segment sum
// N nodes, 80 f32 ft (32 scalar + 16 x 3-vec), NG=1024 graphs (sorted batch_index), F=664.
//
// Math identities (validated rounds 1-4, absmax 3.9e-3):
//   selu const term cancels in softmax; pre-scale s by sqrt(log2e), v by sqrt(log2e/sqrt3)
//   so pair products are f*log2e -> exp2 directly. out_g = (sum nf*ex)/z_g.
//
// Round-16: pair-split, SPILL-FREE attempt. r6 and r15 both ran the split under
//   launch_bounds(...,8) = VGPR cap 64 while staging row4[20] (80 regs) -> scratch spill
//   (WRITE 136/88 MB) confounded both. The split has never been tested clean. This round:
//   r12's exact clean recipe (TPB-phase staging: s2 built+PINNED, scalar triangle, THEN
//   rv->vp after s2 dead; phase 2 NCHUNK=6, NPB=128) with 2 lanes/node at TPB=256,
//   bounds(256,4) = cap 128. Per-lane triangle work halves (136+36 f2-iters), waves double
//   to 9375 (4-wave blocks pack cleanly), grid stays 2344.
//   Falsifiers: WRITE>35MB = spilled again (abandon lever); occupancy up but main ~84 =
//   stall scales with TLP (shared-resource) -> pivot to overhead reduction + p2 ablation.

typedef float f2 __attribute__((ext_vector_type(2)));

#define C0 32
#define C1 16
#define NODE_F 80
#define NG_CONST 1024
#define NPB 128                 // nodes per block
#define TPB 256                 // 2 lanes per node
#define NCHUNK 6                // phase-2 node chunks (NCHUNK*20 <= TPB)

#define SELU_SCALE 1.0507009873554804934193349852946
#define SELU_ALPHA 1.6732632423543772848170429916717
#define LOG2E      1.4426950408889634073599246810019

#define CS_SCALE 1.2011224087864498f    // sqrt(log2e)
#define CV_SCALE 0.91271231102878545f   // sqrt(log2e/sqrt(3))

// ws float layout:
//   [0, 81920)        S accum: [1024 graphs][80 ch]
//   [81920, 82944)    z accum: [1024]
//   [82944, 84224)    Wpad: 512 f2 scalar rows (32x16) then 128 f2 vec rows (16x8)
#define WS_S 0
#define WS_Z 81920
#define WS_W 82944

__device__ __forceinline__ int ks_idx(int i, int j) { return i * C0 - (i * (i - 1)) / 2 + (j - i); }
__device__ __forceinline__ int kv_idx(int i, int j) { return 528 + i * C1 - (i * (i - 1)) / 2 + (j - i); }

// zero the accumulators + build padded W tables
__global__ __launch_bounds__(256) void prep_kernel(
    const float* __restrict__ W, float* __restrict__ ws)
{
    const int t = blockIdx.x * blockDim.x + threadIdx.x;
    if (t < 82944) {
        ws[t] = 0.0f;                       // S and z
    } else {
        int u = t - 82944;
        if (u < 512) {                      // Ws: i in [0,32), q in [0,16)
            int i = u >> 4, q = u & 15;
            int j0 = 2 * q, j1 = 2 * q + 1;
            ws[WS_W + 2 * u]     = (j0 >= i) ? W[ks_idx(i, j0)] : 0.0f;
            ws[WS_W + 2 * u + 1] = (j1 >= i) ? W[ks_idx(i, j1)] : 0.0f;
        } else if (u < 640) {               // Wv: i in [0,16), q in [0,8)
            int v = u - 512;
            int i = v >> 3, q = v & 7;
            int j0 = 2 * q, j1 = 2 * q + 1;
            ws[WS_W + 1024 + 2 * v]     = (j0 >= i) ? W[kv_idx(i, j0)] : 0.0f;
            ws[WS_W + 1024 + 2 * v + 1] = (j1 >= i) ? W[kv_idx(i, j1)] : 0.0f;
        }
    }
}

__global__ __launch_bounds__(TPB, 4) void main_kernel(
    const float* __restrict__ nf, const int* __restrict__ bi,
    const float* __restrict__ ws, float* __restrict__ S,
    float* __restrict__ z, int N)
{
    __shared__ __align__(16) float Wlds[1280];
    __shared__ float exl[NPB];
    __shared__ int   bil[NPB];

    const int tid  = threadIdx.x;
    const int base = blockIdx.x * NPB;
    const float4* g4 = (const float4*)nf;

    #pragma unroll
    for (int u = tid; u < 1280; u += TPB) Wlds[u] = ws[WS_W + u];

    if (tid < NPB) {
        int idx = base + tid;
        bil[tid] = bi[idx > N - 1 ? N - 1 : idx];
    }

    const int  ln    = tid >> 1;            // local node 0..127
    const int  p     = tid & 1;             // parity: which half of the triangle rows
    const int  n     = base + ln;
    const bool valid = (n < N);
    const int  nn    = valid ? n : (N - 1);
    __syncthreads();                        // Wlds + bil ready

    const float4* gp = g4 + (size_t)nn * 20;
    const f2* WsL = (const f2*)Wlds;          // 512 f2
    const f2* WvL = (const f2*)(Wlds + 1024); // 128 f2

    // ---- phase 1: scalar half -> s2 in registers, PINNED (r12 recipe) ----
    f2 s2[C0 / 2];
    {
        float4 rs[8];
        #pragma unroll
        for (int q = 0; q < 8; ++q) rs[q] = gp[q];
        #pragma unroll
        for (int q = 0; q < 8; ++q) {
            s2[2 * q]     = f2{rs[q].x, rs[q].y} * CS_SCALE;
            s2[2 * q + 1] = f2{rs[q].z, rs[q].w} * CS_SCALE;
        }
    }
    #pragma unroll
    for (int q = 0; q < C0 / 2; ++q) asm volatile("" : "+v"(s2[q]));

    f2 accA[2], accB[2];
    accA[0] = (f2)0.f; accA[1] = (f2)0.f; accB[0] = (f2)0.f; accB[1] = (f2)0.f;

    // scalar triangle: lane handles rows i = 2k+p, k=0..15 (136 f2-iters per lane)
    #pragma unroll
    for (int k = 0; k < C0 / 2; ++k) {
        const int i = 2 * k + p;                    // lane-dependent row
        const float si = p ? s2[k].y : s2[k].x;
        const f2 si2 = f2{si, si};
        #pragma unroll
        for (int q = k; q < C0 / 2; ++q) {
            f2 f = si2 * s2[q];
            f2 pp = __builtin_elementwise_max(f, (f2)0.f);
            f2 m  = __builtin_elementwise_min(f, (f2)0.f);
            f2 e; e.x = __builtin_amdgcn_exp2f(m.x);
                  e.y = __builtin_amdgcn_exp2f(m.y);
            f2 w = WsL[i * 16 + q];             // 2 rows/wave 128B apart: 2-way, near-free
            accA[q & 1] = __builtin_elementwise_fma(w, pp, accA[q & 1]);
            accB[q & 1] = __builtin_elementwise_fma(w, e, accB[q & 1]);
        }
    }

    // vector half: load AFTER s2 is dead (never 80 regs live at once)
    float4 rv[12];
    #pragma unroll
    for (int q = 0; q < 12; ++q) rv[q] = gp[8 + q];

    f2 vp[C1 / 2][3];
    {
        const float* rvf = (const float*)rv;
        #pragma unroll
        for (int q = 0; q < C1 / 2; ++q) {
            #pragma unroll
            for (int c = 0; c < 3; ++c)
                vp[q][c] = f2{rvf[6 * q + c], rvf[6 * q + 3 + c]} * CV_SCALE;
        }
    }

    // vector triangle: lane handles rows i = 2k+p, k=0..7 (36 f2-iters per lane)
    #pragma unroll
    for (int k = 0; k < C1 / 2; ++k) {
        const int i = 2 * k + p;
        const float vi0 = p ? vp[k][0].y : vp[k][0].x;
        const float vi1 = p ? vp[k][1].y : vp[k][1].x;
        const float vi2 = p ? vp[k][2].y : vp[k][2].x;
        #pragma unroll
        for (int q = k; q < C1 / 2; ++q) {
            f2 f = vp[q][0] * f2{vi0, vi0};
            f = __builtin_elementwise_fma(vp[q][1], f2{vi1, vi1}, f);
            f = __builtin_elementwise_fma(vp[q][2], f2{vi2, vi2}, f);
            f2 pp = __builtin_elementwise_max(f, (f2)0.f);
            f2 m  = __builtin_elementwise_min(f, (f2)0.f);
            f2 e; e.x = __builtin_amdgcn_exp2f(m.x);
                  e.y = __builtin_amdgcn_exp2f(m.y);
            f2 w = WvL[i * 8 + q];
            accA[q & 1] = __builtin_elementwise_fma(w, pp, accA[q & 1]);
            accB[q & 1] = __builtin_elementwise_fma(w, e, accB[q & 1]);
        }
    }

    float A1 = accA[0].x + accA[0].y + accA[1].x + accA[1].y;
    float A2 = accB[0].x + accB[0].y + accB[1].x + accB[1].y;
    A1 += __shfl_xor(A1, 1);                // combine lane-pair halves
    A2 += __shfl_xor(A2, 1);
    const float l2 = fmaf((float)SELU_SCALE, A1,
                          (float)(SELU_SCALE * SELU_ALPHA * LOG2E) * A2);
    if (p == 0) exl[ln] = valid ? __builtin_amdgcn_exp2f(l2) : 0.0f;
    __syncthreads();

    // ---- phase 2 (tid<120): VERBATIM r12 -- 6 chunks x 20 cols, flush per graph run ----
    if (tid < NCHUNK * 20) {
        const int no = tid / 20;       // 0..5
        const int c4 = tid % 20;
        const int nb = (no * NPB) / NCHUNK;
        const int ne = ((no + 1) * NPB) / NCHUNK;
        int cg = bil[nb];
        float4 acc = make_float4(0.f, 0.f, 0.f, 0.f);
        float  zacc = 0.0f;

        for (int nl = nb; nl < ne; ++nl) {
            const int g2 = bil[nl];
            if (g2 != cg) {
                unsafeAtomicAdd(&S[cg * NODE_F + c4 * 4 + 0], acc.x);
                unsafeAtomicAdd(&S[cg * NODE_F + c4 * 4 + 1], acc.y);
                unsafeAtomicAdd(&S[cg * NODE_F + c4 * 4 + 2], acc.z);
                unsafeAtomicAdd(&S[cg * NODE_F + c4 * 4 + 3], acc.w);
                if (c4 == 0) unsafeAtomicAdd(&z[cg], zacc);
                acc = make_float4(0.f, 0.f, 0.f, 0.f); zacc = 0.0f; cg = g2;
            }
            int idx = base + nl; if (idx > N - 1) idx = N - 1;   // pad nodes have w=0
            const float  w = exl[nl];
            const float4 v = g4[(size_t)idx * 20 + c4];
            acc.x = fmaf(v.x, w, acc.x); acc.y = fmaf(v.y, w, acc.y);
            acc.z = fmaf(v.z, w, acc.z); acc.w = fmaf(v.w, w, acc.w);
            zacc += w;
        }
        unsafeAtomicAdd(&S[cg * NODE_F + c4 * 4 + 0], acc.x);
        unsafeAtomicAdd(&S[cg * NODE_F + c4 * 4 + 1], acc.y);
        unsafeAtomicAdd(&S[cg * NODE_F + c4 * 4 + 2], acc.z);
        unsafeAtomicAdd(&S[cg * NODE_F + c4 * 4 + 3], acc.w);
        if (c4 == 0) unsafeAtomicAdd(&z[cg], zacc);
    }
}

__global__ __launch_bounds__(256) void divide_kernel(
    const float* __restrict__ S, const float* __restrict__ z,
    float* __restrict__ out)
{
    const int t = blockIdx.x * blockDim.x + threadIdx.x;
    if (t >= NG_CONST * NODE_F) return;
    const float zz = z[t / NODE_F];
    out[t] = (zz > 0.0f) ? (S[t] / zz) : 0.0f;
}

extern "C" void kernel_launch(void* const* d_in, const int* in_sizes, int n_in,
                              void* d_out, int out_size, void* d_ws, size_t ws_size,
                              hipStream_t stream) {
    const float* nf = (const float*)d_in[0];   // (N, 80) f32
    const int*   bi = (const int*)d_in[1];     // (N,) i32 sorted
    // d_in[2] = num_graphs (static 1024)
    const float* W  = (const float*)d_in[3];   // (664,) f32
    float* out = (float*)d_out;

    const int N = in_sizes[0] / NODE_F;
    float* ws = (float*)d_ws;
    float* S  = ws + WS_S;
    float* z  = ws + WS_Z;

    hipLaunchKernelGGL(prep_kernel, dim3(332), dim3(256), 0, stream, W, ws);
    hipLaunchKernelGGL(main_kernel, dim3((N + NPB - 1) / NPB), dim3(TPB), 0, stream,
                       nf, bi, ws, S, z, N);
    hipLaunchKernelGGL(divide_kernel, dim3((NG_CONST * NODE_F + 255) / 256), dim3(256),
                       0, stream, S, z, out);
}